// Round 14
// baseline (48.343 us; speedup 1.0000x reference)
//
#include <hip/hip_runtime.h>

typedef __attribute__((ext_vector_type(4))) float f32x4;
typedef unsigned int u32;
typedef long i64;

#define NROWS 8192
#define HALF  4096
#define DIM   256
#define TEMP_INV 2.0f                 // 1/temperature
#define NBT 64                        // 8192/128 tiles per side
#define NTILE (NBT * (NBT + 1) / 2)   // 2080 triangular tiles
#define NPAIR (NTILE / 2)             // 1040 blocks, 2 tiles each
#define NSLAB 128                     // 64 row-slots + 64 col-slots

#define BARRIER() asm volatile("s_barrier" ::: "memory")
#define WAITV(n)  asm volatile("s_waitcnt vmcnt(" #n ")" ::: "memory")

// ------- kernel 1: normalize -> fp8 e4m3, zero slab + ticket ----------------
__global__ __launch_bounds__(256) void normalize_k(const float* __restrict__ zi,
                                                   const float* __restrict__ zj,
                                                   u32* __restrict__ zn8,
                                                   float4* __restrict__ slab4,
                                                   u32* __restrict__ ticket) {
    const int row  = blockIdx.x * 4 + (threadIdx.x >> 6);
    const int lane = threadIdx.x & 63;
    const float* src = (row < HALF) ? (zi + (size_t)row * DIM)
                                    : (zj + (size_t)(row - HALF) * DIM);
    float4 v = reinterpret_cast<const float4*>(src)[lane];
    float ss = v.x * v.x + v.y * v.y + v.z * v.z + v.w * v.w;
    #pragma unroll
    for (int m = 32; m; m >>= 1) ss += __shfl_xor(ss, m);
    const float inv = 1.0f / fmaxf(sqrtf(ss), 1e-8f);
    u32 pk = __builtin_amdgcn_cvt_pk_fp8_f32(v.x * inv, v.y * inv, 0, false);
    pk     = __builtin_amdgcn_cvt_pk_fp8_f32(v.z * inv, v.w * inv, pk, true);
    zn8[(size_t)row * (DIM / 4) + lane] = pk;
    const int gt = blockIdx.x * 256 + threadIdx.x;
    if (gt < (NSLAB * NROWS) / 4)
        slab4[gt] = float4{0.f, 0.f, 0.f, 0.f};
    if (gt == 0) *ticket = 0;
}

// ------- kernel 2: tile-pair fp8 triangular GEMM ----------------------------
// Each block: 2 consecutive triangle tiles. A (32x256 fp8, 32 VGPR) loaded
// once per strip (97% of pairs share it). Tile1's B-stage issues right after
// tile0's B-free barrier; its latency hides under tile0's epilogue (WAITV(2):
// only the 2 row-sum stores are younger). Fast fold has no per-element
// compares; diag/isPos corrections in a block-uniform rare branch.
__device__ __forceinline__ void gload16(const void* g, void* lds) {
    __builtin_amdgcn_global_load_lds(
        (const __attribute__((address_space(1))) u32*)g,
        (__attribute__((address_space(3))) u32*)lds, 16, 0, 0);
}

__global__ __launch_bounds__(256, 4) void gemm_exp_rowsum(
        const unsigned char* __restrict__ zn8,
        float* __restrict__ slab, float* __restrict__ pos) {
    // XCD-aware bijective swizzle on the PAIR index (1040 = 8 * 130)
    const int p0 = blockIdx.x;
    const int p  = (p0 & 7) * (NPAIR / 8) + (p0 >> 3);
    const int t0 = p * 2;
    // Triangular decode: t0 -> (by, bx), by <= bx < 64; tile1 = next in row-major
    int by = (int)((129.0f - sqrtf(129.0f * 129.0f - 8.0f * (float)t0)) * 0.5f);
    while (by * (129 - by) / 2 > t0) --by;
    while ((by + 1) * (129 - (by + 1)) / 2 <= t0) ++by;
    const int bx = by + (t0 - by * (129 - by) / 2);
    int by1 = by, bx1 = bx + 1;
    if (bx1 >= NBT) { by1 = by + 1; bx1 = by1; }
    const bool diag0 = (by == bx),   isPos0 = (bx - by == 32);
    const bool diag1 = (by1 == bx1), isPos1 = (bx1 - by1 == 32);

    __shared__ char  LDSB[32768];   // B-tile buffer
    __shared__ float colred[512];   // cross-wave col-sum exchange

    const int tid  = threadIdx.x;
    const int w    = tid >> 6;      // 0..3, wave owns rows [w*32, +32)
    const int lane = tid & 63;

    i64 ar[2][8];
    auto loadA = [&](int byy) {
        const unsigned char* aBase = zn8
            + (size_t)(byy * 128 + w * 32 + (lane & 15)) * DIM + (lane >> 4) * 8;
        #pragma unroll
        for (int mi = 0; mi < 2; ++mi)
            #pragma unroll
            for (int ks = 0; ks < 8; ++ks)
                ar[mi][ks] = *reinterpret_cast<const i64*>(
                    aBase + (size_t)mi * 16 * DIM + ks * 32);
    };
    auto stageB = [&](int bxx) {     // 8 gload16/wave, both-sides 16B swizzle
        #pragma unroll
        for (int j = 0; j < 8; ++j) {
            const int r  = (j * 4 + w) * 4 + (lane >> 4);
            const int gq = (lane & 15) ^ (r & 7);
            gload16(zn8 + (size_t)(bxx * 128 + r) * DIM + gq * 16,
                    LDSB + (j * 4 + w) * 1024);
        }
    };

    const int rowByte = (lane & 15) * 256 + ((lane >> 4) & 1) * 8;
    const int k8      = lane & 7;
    const int hq      = (lane >> 4) >> 1;

    float rs[2][4], csv[8], posv[2];

    auto computeFold = [&](bool dg, bool ip) {
        #pragma unroll
        for (int mi = 0; mi < 2; ++mi)
            #pragma unroll
            for (int v = 0; v < 4; ++v) rs[mi][v] = 0.f;
        posv[0] = posv[1] = 0.f;
        #pragma clang loop unroll(disable)
        for (int ni = 0; ni < 8; ++ni) {
            f32x4 a0 = {0.f,0.f,0.f,0.f}, a1 = {0.f,0.f,0.f,0.f};
            #pragma unroll
            for (int ks = 0; ks < 8; ++ks) {
                const int off = ni * 4096 + rowByte + (((ks * 2 + hq) ^ k8) << 4);
                const i64 bv = *reinterpret_cast<const i64*>(LDSB + off);
                a0 = __builtin_amdgcn_mfma_f32_16x16x32_fp8_fp8(ar[0][ks], bv, a0, 0, 0, 0);
                a1 = __builtin_amdgcn_mfma_f32_16x16x32_fp8_fp8(ar[1][ks], bv, a1, 0, 0, 0);
            }
            float cacc = 0.f;
            #pragma unroll
            for (int v = 0; v < 4; ++v) {          // fast path: no compares
                const float e0 = __expf(TEMP_INV * a0[v]);
                const float e1 = __expf(TEMP_INV * a1[v]);
                rs[0][v] += e0; rs[1][v] += e1;
                cacc += e0 + e1;
            }
            if (dg || ip) {                        // uniform rare branch
                #pragma unroll
                for (int v = 0; v < 4; ++v) {
                    const bool lc = ((lane & 15) == ((lane >> 4) * 4 + v));
                    const bool c0 = (ni == w * 2)     && lc;
                    const bool c1 = (ni == w * 2 + 1) && lc;
                    if (dg) {
                        if (c0) { const float e = __expf(TEMP_INV * a0[v]); rs[0][v] -= e; cacc -= e; }
                        if (c1) { const float e = __expf(TEMP_INV * a1[v]); rs[1][v] -= e; cacc -= e; }
                    } else {
                        if (c0) posv[0] = a0[v];
                        if (c1) posv[1] = a1[v];
                    }
                }
            }
            csv[ni] = cacc;
        }
    };

    auto rowStores = [&](int byy, int bxx) {       // 2 store instr per wave
        float* rowSlot = slab + (size_t)bxx * NROWS + byy * 128 + w * 32;
        #pragma unroll
        for (int mi = 0; mi < 2; ++mi) {
            f32x4 r;
            #pragma unroll
            for (int v = 0; v < 4; ++v) {
                float s = rs[mi][v];
                s += __shfl_xor(s, 1);
                s += __shfl_xor(s, 2);
                s += __shfl_xor(s, 4);
                s += __shfl_xor(s, 8);
                r[v] = s;
            }
            if ((lane & 15) == 0)
                *reinterpret_cast<f32x4*>(rowSlot + mi * 16 + (lane >> 4) * 4) = r;
        }
    };
    auto colredWrite = [&]() {
        #pragma unroll
        for (int g = 0; g < 8; ++g) {
            float c = csv[g];
            c += __shfl_xor(c, 16);
            c += __shfl_xor(c, 32);
            if (lane < 16) colred[w * 128 + g * 16 + lane] = c;
        }
    };
    auto posStore = [&](int byy) {
        const int vq = (lane & 15) - (lane >> 4) * 4;
        if (vq >= 0 && vq < 4) {
            #pragma unroll
            for (int mi = 0; mi < 2; ++mi) {
                const int Rg = byy * 128 + w * 32 + mi * 16 + (lane & 15);
                pos[Rg] = posv[mi];
                pos[Rg + HALF] = posv[mi];
            }
        }
    };

    // ---------------- tile 0 ----------------
    loadA(by);
    stageB(bx);
    WAITV(0); BARRIER();
    computeFold(diag0, isPos0);
    BARRIER();                       // B buffer free
    // ---------------- tile 1 prep (latency hidden under tile-0 epilogue) ----
    stageB(bx1);
    if (by1 != by) loadA(by1);
    // ---------------- tile 0 epilogue ----------------
    rowStores(by, bx);               // +2 vmcnt (uniform)
    colredWrite();
    __syncthreads();
    float colv = 0.f;
    if (tid < 128)
        colv = colred[tid] + colred[128 + tid] + colred[256 + tid] + colred[384 + tid];
    WAITV(2); BARRIER();             // stage1(+A2) landed; 2 row stores pending
    if (tid < 128)
        slab[(size_t)(64 + by) * NROWS + bx * 128 + tid] = diag0 ? 0.f : colv;
    if (isPos0) posStore(by);
    // ---------------- tile 1 ----------------
    computeFold(diag1, isPos1);
    rowStores(by1, bx1);
    colredWrite();
    __syncthreads();
    if (tid < 128) {
        const float cv = colred[tid] + colred[128 + tid]
                       + colred[256 + tid] + colred[384 + tid];
        slab[(size_t)(64 + by1) * NROWS + bx1 * 128 + tid] = diag1 ? 0.f : cv;
    }
    if (isPos1) posStore(by1);
}

// ------- kernel 3: reduce slab + fused last-block final sum -----------------
__global__ __launch_bounds__(256) void finalize_k(const float* __restrict__ slab,
                                                  const float* __restrict__ pos,
                                                  float* __restrict__ part,
                                                  u32* __restrict__ ticket,
                                                  float* __restrict__ out) {
    const int row = blockIdx.x * 256 + threadIdx.x;
    float d = 0.f;
    #pragma unroll 8
    for (int j = 0; j < NSLAB; ++j)
        d += slab[(size_t)j * NROWS + row];    // coalesced across threads
    float s = logf(d) - TEMP_INV * pos[row];
    __shared__ float red[256];
    red[threadIdx.x] = s;
    __syncthreads();
    #pragma unroll
    for (int m = 128; m; m >>= 1) {
        if (threadIdx.x < m) red[threadIdx.x] += red[threadIdx.x + m];
        __syncthreads();
    }
    __shared__ u32 isLast;
    if (threadIdx.x == 0) {
        part[blockIdx.x] = red[0];
        __threadfence();                       // publish part before counting
        isLast = (atomicAdd(ticket, 1u) == (NROWS / 256) - 1) ? 1u : 0u;
    }
    __syncthreads();
    if (isLast && threadIdx.x < 64) {
        // coherent reads of all partials via atomic fetch-add(0)
        float v = (threadIdx.x < NROWS / 256)
                  ? atomicAdd(&part[threadIdx.x], 0.0f) : 0.f;
        #pragma unroll
        for (int m = 32; m; m >>= 1) v += __shfl_xor(v, m);
        if (threadIdx.x == 0) out[0] = v * (1.0f / NROWS);
    }
}

extern "C" void kernel_launch(void* const* d_in, const int* in_sizes, int n_in,
                              void* d_out, int out_size, void* d_ws, size_t ws_size,
                              hipStream_t stream) {
    const float* zi = (const float*)d_in[0];
    const float* zj = (const float*)d_in[1];
    float* out = (float*)d_out;

    // workspace: zn8 fp8 [8192][256] (2 MiB) | slab f32 [128][8192] (4 MiB)
    //            | pos f32 [8192] | part f32 [32] | ticket u32
    unsigned char* zn8 = (unsigned char*)d_ws;
    float* slab = (float*)((char*)d_ws + (size_t)NROWS * DIM);
    float* pos  = slab + (size_t)NSLAB * NROWS;
    float* part = pos + NROWS;
    u32* ticket = (u32*)(part + 32);

    normalize_k<<<NROWS / 4, 256, 0, stream>>>(zi, zj, (u32*)zn8, (float4*)slab, ticket);
    gemm_exp_rowsum<<<NPAIR, 256, 0, stream>>>(zn8, slab, pos);
    finalize_k<<<NROWS / 256, 256, 0, stream>>>(slab, pos, part, ticket, out);
}

// Round 15
// 44.419 us; speedup vs baseline: 1.0883x; 1.0883x over previous
//
#include <hip/hip_runtime.h>

typedef __attribute__((ext_vector_type(4))) float f32x4;
typedef unsigned int u32;
typedef long i64;

#define NROWS 8192
#define HALF  4096
#define DIM   256
#define TEMP_INV 2.0f                 // 1/temperature
#define NBT 64                        // 8192/128 tiles per side
#define NBLK (NBT * (NBT + 1) / 2)    // 2080 triangular tiles
#define NSLAB 128                     // 64 row-slots + 64 col-slots

#define BARRIER() asm volatile("s_barrier" ::: "memory")
#define WAITV(n)  asm volatile("s_waitcnt vmcnt(" #n ")" ::: "memory")

// ------- kernel 1: normalize rows -> fp8 e4m3, and zero the slab ------------
__global__ __launch_bounds__(256) void normalize_k(const float* __restrict__ zi,
                                                   const float* __restrict__ zj,
                                                   u32* __restrict__ zn8,
                                                   float4* __restrict__ slab4) {
    const int row  = blockIdx.x * 4 + (threadIdx.x >> 6);
    const int lane = threadIdx.x & 63;
    const float* src = (row < HALF) ? (zi + (size_t)row * DIM)
                                    : (zj + (size_t)(row - HALF) * DIM);
    float4 v = reinterpret_cast<const float4*>(src)[lane];
    float ss = v.x * v.x + v.y * v.y + v.z * v.z + v.w * v.w;
    #pragma unroll
    for (int m = 32; m; m >>= 1) ss += __shfl_xor(ss, m);
    const float inv = 1.0f / fmaxf(sqrtf(ss), 1e-8f);
    u32 pk = __builtin_amdgcn_cvt_pk_fp8_f32(v.x * inv, v.y * inv, 0, false);
    pk     = __builtin_amdgcn_cvt_pk_fp8_f32(v.z * inv, v.w * inv, pk, true);
    zn8[(size_t)row * (DIM / 4) + lane] = pk;
    const int gt = blockIdx.x * 256 + threadIdx.x;
    if (gt < (NSLAB * NROWS) / 4)
        slab4[gt] = float4{0.f, 0.f, 0.f, 0.f};
}

// ------- kernel 2: single-barrier fp8 triangular GEMM, ping-pong ni-loop ----
// A (32x256 fp8) in 32 VGPR/lane; full B-tile (128x256 = 32 KB) staged once;
// one vmcnt(0)+barrier; then a rolled x2 ni-loop with named ping-pong B-frag
// buffers: prefetch ni+1's 8 ds_read_b64 while ni's 16 MFMA + fold run.
__device__ __forceinline__ void gload16(const void* g, void* lds) {
    __builtin_amdgcn_global_load_lds(
        (const __attribute__((address_space(1))) u32*)g,
        (__attribute__((address_space(3))) u32*)lds, 16, 0, 0);
}

__global__ __launch_bounds__(256, 4) void gemm_exp_rowsum(
        const unsigned char* __restrict__ zn8,
        float* __restrict__ slab, float* __restrict__ pos) {
    // XCD-aware bijective swizzle (2080 = 8 * 260)
    const int b0 = blockIdx.x;
    const int b  = (b0 & 7) * (NBLK / 8) + (b0 >> 3);
    // Triangular decode: b -> (by, bx), by <= bx < 64
    int by = (int)((129.0f - sqrtf(129.0f * 129.0f - 8.0f * (float)b)) * 0.5f);
    while (by * (129 - by) / 2 > b) --by;
    while ((by + 1) * (129 - (by + 1)) / 2 <= b) ++by;
    const int bx = by + (b - by * (129 - by) / 2);
    const bool diag  = (by == bx);
    const bool isPos = (bx - by == 32);

    const int rowBase = by * 128;
    const int colBase = bx * 128;

    __shared__ char LDSB[32768];    // full B-tile; reused for col-reduce

    const int tid  = threadIdx.x;
    const int w    = tid >> 6;      // 0..3, wave owns rows [w*32, +32)
    const int lane = tid & 63;

    // ---- A -> registers: frag(mi,ks) = 8 fp8 of row w*32+mi*16+(lane&15),
    // k in [ks*32 + (lane>>4)*8, +8)
    i64 ar[2][8];
    const unsigned char* aBase = zn8
        + (size_t)(rowBase + w * 32 + (lane & 15)) * DIM + (lane >> 4) * 8;
    #pragma unroll
    for (int mi = 0; mi < 2; ++mi)
        #pragma unroll
        for (int ks = 0; ks < 8; ++ks)
            ar[mi][ks] = *reinterpret_cast<const i64*>(
                aBase + (size_t)mi * 16 * DIM + ks * 32);

    // ---- stage full B-tile: LDS row r at r*256; 16B unit u holds global
    // unit u ^ (r&7) (both-sides swizzle; spreads 8 bank-groups on read).
    #pragma unroll
    for (int j = 0; j < 8; ++j) {
        const int r  = (j * 4 + w) * 4 + (lane >> 4);
        const int gq = (lane & 15) ^ (r & 7);
        gload16(zn8 + (size_t)(colBase + r) * DIM + gq * 16,
                LDSB + (j * 4 + w) * 1024);
    }
    WAITV(0);      // A regs + all LDS writes landed
    BARRIER();     // whole B-tile visible; no further inter-wave sync

    const int rowByte = (lane & 15) * 256 + ((lane >> 4) & 1) * 8;
    const int k8      = lane & 7;
    const int hq      = (lane >> 4) >> 1;

    float rs[2][4] = {};
    float csv[8];
    float posv[2]  = {0.f, 0.f};

    auto rdNi = [&](i64* buf, int ni) {
        #pragma unroll
        for (int ks = 0; ks < 8; ++ks) {
            const int off = ni * 4096 + rowByte + (((ks * 2 + hq) ^ k8) << 4);
            buf[ks] = *reinterpret_cast<const i64*>(LDSB + off);
        }
    };
    auto doNi = [&](const i64* buf, int ni) {
        f32x4 a0 = {0.f, 0.f, 0.f, 0.f}, a1 = {0.f, 0.f, 0.f, 0.f};
        #pragma unroll
        for (int ks = 0; ks < 8; ++ks) {
            a0 = __builtin_amdgcn_mfma_f32_16x16x32_fp8_fp8(ar[0][ks], buf[ks], a0, 0, 0, 0);
            a1 = __builtin_amdgcn_mfma_f32_16x16x32_fp8_fp8(ar[1][ks], buf[ks], a1, 0, 0, 0);
        }
        float cacc = 0.f;
        #pragma unroll
        for (int v = 0; v < 4; ++v) {
            const int C  = ni * 16 + (lane & 15);
            const int R0 = w * 32 + (lane >> 4) * 4 + v;
            const int R1 = R0 + 16;
            float e0 = __expf(TEMP_INV * a0[v]);
            float e1 = __expf(TEMP_INV * a1[v]);
            if (isPos && R0 == C) posv[0] = a0[v];
            if (isPos && R1 == C) posv[1] = a1[v];
            if (diag && R0 == C) e0 = 0.f;
            if (diag && R1 == C) e1 = 0.f;
            rs[0][v] += e0; rs[1][v] += e1;
            cacc += e0 + e1;
        }
        csv[ni] = cacc;
    };

    // ping-pong pipelined ni-loop: prefetch ni+1 while computing ni
    i64 bA[8], bB[8];
    rdNi(bA, 0);
    #pragma clang loop unroll(disable)
    for (int nn = 0; nn < 4; ++nn) {
        const int e = nn * 2, o = e + 1;
        rdNi(bB, o);               // prefetch odd while even computes
        doNi(bA, e);
        if (nn < 3) rdNi(bA, o + 1);  // prefetch next even while odd computes
        doNi(bB, o);
    }

    // ---- row sums: allreduce across the 16 col-lanes, coalesced store
    float* rowSlot = slab + (size_t)bx * NROWS + rowBase + w * 32;
    #pragma unroll
    for (int mi = 0; mi < 2; ++mi) {
        f32x4 r;
        #pragma unroll
        for (int v = 0; v < 4; ++v) {
            float s = rs[mi][v];
            s += __shfl_xor(s, 1);
            s += __shfl_xor(s, 2);
            s += __shfl_xor(s, 4);
            s += __shfl_xor(s, 8);
            r[v] = s;
        }
        if ((lane & 15) == 0)
            *reinterpret_cast<f32x4*>(rowSlot + mi * 16 + (lane >> 4) * 4) = r;
    }

    // ---- col sums: per-wave reduce, cross-wave via reused LDS
    __syncthreads();                    // all B reads done; LDSB reusable
    float* colred = reinterpret_cast<float*>(LDSB);
    #pragma unroll
    for (int g = 0; g < 8; ++g) {       // col = g*16 + (lane&15)
        float c = csv[g];
        c += __shfl_xor(c, 16);
        c += __shfl_xor(c, 32);
        if (lane < 16) colred[w * 128 + g * 16 + lane] = c;
    }
    __syncthreads();
    if (tid < 128) {
        const float sum = colred[tid] + colred[128 + tid]
                        + colred[256 + tid] + colred[384 + tid];
        // diag tile fully covered by row sums -> keep slot zero-consistent
        slab[(size_t)(64 + by) * NROWS + colBase + tid] = diag ? 0.f : sum;
    }

    // ---- positives: tile diagonal of isPos blocks (pre-exp values)
    if (isPos) {
        const int vq = (lane & 15) - (lane >> 4) * 4;
        if (vq >= 0 && vq < 4) {
            #pragma unroll
            for (int mi = 0; mi < 2; ++mi) {
                const int Rg = rowBase + w * 32 + mi * 16 + (lane & 15);
                pos[Rg] = posv[mi];
                pos[Rg + HALF] = posv[mi];
            }
        }
    }
}

// ------- kernel 3: reduce all 128 slab slots (zero-inited) ------------------
__global__ __launch_bounds__(256) void finalize_k(const float* __restrict__ slab,
                                                  const float* __restrict__ pos,
                                                  float* __restrict__ part) {
    const int row = blockIdx.x * 256 + threadIdx.x;
    float d = 0.f;
    #pragma unroll 8
    for (int j = 0; j < NSLAB; ++j)
        d += slab[(size_t)j * NROWS + row];    // coalesced across threads
    float s = logf(d) - TEMP_INV * pos[row];
    __shared__ float red[256];
    red[threadIdx.x] = s;
    __syncthreads();
    #pragma unroll
    for (int m = 128; m; m >>= 1) {
        if (threadIdx.x < m) red[threadIdx.x] += red[threadIdx.x + m];
        __syncthreads();
    }
    if (threadIdx.x == 0) part[blockIdx.x] = red[0];
}

// ------- kernel 4: sum 32 partials (deterministic, no atomics) --------------
__global__ __launch_bounds__(64) void sum_k(const float* __restrict__ part,
                                            float* __restrict__ out) {
    float v = (threadIdx.x < 32) ? part[threadIdx.x] : 0.f;
    #pragma unroll
    for (int m = 32; m; m >>= 1) v += __shfl_xor(v, m);
    if (threadIdx.x == 0) out[0] = v * (1.0f / NROWS);
}

extern "C" void kernel_launch(void* const* d_in, const int* in_sizes, int n_in,
                              void* d_out, int out_size, void* d_ws, size_t ws_size,
                              hipStream_t stream) {
    const float* zi = (const float*)d_in[0];
    const float* zj = (const float*)d_in[1];
    float* out = (float*)d_out;

    // workspace: zn8 fp8 [8192][256] (2 MiB) | slab f32 [128][8192] (4 MiB)
    //            | pos f32 [8192] | part f32 [32]
    unsigned char* zn8 = (unsigned char*)d_ws;
    float* slab = (float*)((char*)d_ws + (size_t)NROWS * DIM);
    float* pos  = slab + (size_t)NSLAB * NROWS;
    float* part = pos + NROWS;

    normalize_k<<<NROWS / 4, 256, 0, stream>>>(zi, zj, (u32*)zn8, (float4*)slab);
    gemm_exp_rowsum<<<NBLK, 256, 0, stream>>>(zn8, slab, pos);
    finalize_k<<<NROWS / 256, 256, 0, stream>>>(slab, pos, part);
    sum_k<<<1, 64, 0, stream>>>(part, out);
}